// Round 10
// baseline (164.571 us; speedup 1.0000x reference)
//
#include <hip/hip_runtime.h>

// GCN 2-layer + mean-pool + FC for MI355X (gfx950).
// Round 10: feature-partitioned gather2. ts (6.4MB bf16) misses the 4MB
// per-XCD L2 under random row gathers. Group g=blockIdx&7 (XCD round-robin)
// owns features [8g,8g+8) = one 16B uint4 per row -> per-XCD ts footprint
// 0.8MB (L2-resident). Each group sweeps all nodes/edges; eidx/rs re-reads
// are sequential streams (~25MB total, ~4us at HBM BW).
//
// Pipeline:
//   zero cnt+gacc
//   count (XCD dst-partitioned); bsum+scan2 -> rs/cur, dis, xs = x*dis
//   csr (XCD dst-partitioned): eidx[pos] = src
//   aggx[i] = dis[i]*(sum xs[s] + xs[i])
//   mlp:  ts[i,:] = bf16( dis[i] * ( relu(aggx[i]@W1+b1) @ W2 ) )
//   gather2 (XCD feature-partitioned): h2 = relu(dis*(sum ts[s]+ts[i])+b2)
//   out = gacc/N @ Wfc + bfc

#define NXCD 8

__device__ inline unsigned short f2bf_rne(float f) {
    unsigned u = __float_as_uint(f);
    return (unsigned short)((u + 0x7FFFu + ((u >> 16) & 1u)) >> 16);
}
__device__ inline float bflo(unsigned u) { return __uint_as_float(u << 16); }
__device__ inline float bfhi(unsigned u) { return __uint_as_float(u & 0xFFFF0000u); }

// Zero nwords4 int4's (16B each) starting at p (16B-aligned).
__global__ void k_zero(int4* __restrict__ p, int nwords4) {
    int i = blockIdx.x * blockDim.x + threadIdx.x;
    if (i < nwords4) p[i] = make_int4(0, 0, 0, 0);
}

// XCD-partitioned histogram: group (bid&7) counts only dst in its range.
__global__ void k_count_p(const int* __restrict__ dst, int* __restrict__ cnt,
                          int E, int nprg, int n) {
    int grp = blockIdx.x & (NXCD - 1);
    int lo = grp * nprg;
    int hi = min(lo + nprg, n);
    int bIn = blockIdx.x >> 3;
    int nBIn = gridDim.x >> 3;
    for (int e = bIn * blockDim.x + threadIdx.x; e < E; e += nBIn * blockDim.x) {
        int d = dst[e];
        if (d >= lo && d < hi) atomicAdd(&cnt[d], 1);
    }
}

// Phase A: per-block (256-elem chunk) reduction of cnt -> bsum[block].
__global__ void k_bsum(const int* __restrict__ cnt, int* __restrict__ bsum, int n) {
    __shared__ int red[256];
    int tid = threadIdx.x;
    int i = blockIdx.x * 256 + tid;
    red[tid] = (i < n) ? cnt[i] : 0;
    __syncthreads();
    #pragma unroll
    for (int off = 128; off; off >>= 1) {
        if (tid < off) red[tid] += red[tid + off];
        __syncthreads();
    }
    if (tid == 0) bsum[blockIdx.x] = red[0];
}

// Phase B: each block redundantly scans bsum (nb<=256), then scans its own
// 256-elem cnt chunk in LDS; writes rs, cur, dis, xs=x*dis. rs[n]=E.
__global__ void k_scan2(const int* __restrict__ cnt, const int* __restrict__ bsum,
                        int nb, int* __restrict__ rs, int* __restrict__ cur,
                        float* __restrict__ dis, const float* __restrict__ x,
                        float* __restrict__ xs, int n, int Etot) {
    __shared__ int sb[256];
    __shared__ int sc[256];
    int tid = threadIdx.x;
    sb[tid] = (tid < nb) ? bsum[tid] : 0;
    __syncthreads();
    #pragma unroll
    for (int off = 1; off < 256; off <<= 1) {
        int v = (tid >= off) ? sb[tid - off] : 0;
        __syncthreads();
        sb[tid] += v;
        __syncthreads();
    }
    int boff = (blockIdx.x > 0) ? sb[blockIdx.x - 1] : 0;

    int i = blockIdx.x * 256 + tid;
    int c = (i < n) ? cnt[i] : 0;
    sc[tid] = c;
    __syncthreads();
    #pragma unroll
    for (int off = 1; off < 256; off <<= 1) {
        int v = (tid >= off) ? sc[tid - off] : 0;
        __syncthreads();
        sc[tid] += v;
        __syncthreads();
    }
    if (i < n) {
        int r = boff + sc[tid] - c;   // exclusive prefix
        rs[i] = r;
        cur[i] = r;
        float d = rsqrtf((float)c + 1.0f);
        dis[i] = d;
        xs[3 * i + 0] = x[3 * i + 0] * d;
        xs[3 * i + 1] = x[3 * i + 1] * d;
        xs[3 * i + 2] = x[3 * i + 2] * d;
    }
    if (i == 0) rs[n] = Etot;
}

// XCD-partitioned CSR scatter: group (bid&7) owns dst range -> eidx region.
__global__ void k_csr_p(const int* __restrict__ src, const int* __restrict__ dst,
                        int* __restrict__ cur, int* __restrict__ eidx,
                        int E, int nprg, int n) {
    int grp = blockIdx.x & (NXCD - 1);
    int lo = grp * nprg;
    int hi = min(lo + nprg, n);
    int bIn = blockIdx.x >> 3;
    int nBIn = gridDim.x >> 3;
    for (int e = bIn * blockDim.x + threadIdx.x; e < E; e += nBIn * blockDim.x) {
        int d = dst[e];
        if (d >= lo && d < hi) {
            int pos = atomicAdd(&cur[d], 1);
            eidx[pos] = src[e];
        }
    }
}

// Layer-1 aggregate: aggx[i] = dis[i]*(sum_s xs[s] + xs[i]). 8 lanes/node.
__global__ void k_aggx(const float* __restrict__ xs, const float* __restrict__ dis,
                       const int* __restrict__ rs, const int* __restrict__ eidx,
                       float* __restrict__ aggx, int n) {
    int tid = threadIdx.x;
    int sub = tid & 7;
    int gid = blockIdx.x * (blockDim.x >> 3) + (tid >> 3);
    int ng = gridDim.x * (blockDim.x >> 3);
    for (int i = gid; i < n; i += ng) {
        int p0 = rs[i], p1 = rs[i + 1];
        float a0 = 0.f, a1 = 0.f, a2 = 0.f;
        for (int p = p0 + sub; p < p1; p += 8) {
            int s = eidx[p];
            a0 += xs[3 * s + 0];
            a1 += xs[3 * s + 1];
            a2 += xs[3 * s + 2];
        }
        #pragma unroll
        for (int m = 4; m; m >>= 1) {   // reduce within the 8-lane group
            a0 += __shfl_xor(a0, m);
            a1 += __shfl_xor(a1, m);
            a2 += __shfl_xor(a2, m);
        }
        if (sub == 0) {
            float di = dis[i];
            aggx[3 * i + 0] = di * (a0 + xs[3 * i + 0]);
            aggx[3 * i + 1] = di * (a1 + xs[3 * i + 1]);
            aggx[3 * i + 2] = di * (a2 + xs[3 * i + 2]);
        }
    }
}

// Tiled MLP: ts[i,:] = bf16( dis[i] * (relu(a(i)@W1+b1)@W2) ) for a 64-node tile.
// H transposed in LDS [k][node]; W2 chunk [k][feat] in LDS; 4x4 acc/thread.
__global__ __launch_bounds__(256) void k_mlp(const float* __restrict__ aggx,
                                             const float* __restrict__ W1,
                                             const float* __restrict__ b1,
                                             const float* __restrict__ W2,
                                             const float* __restrict__ dis,
                                             unsigned short* __restrict__ ts, int n) {
    __shared__ float sA0[64], sA1[64], sA2[64];
    __shared__ float sW1[3 * 128];
    __shared__ float sb1[128];
    __shared__ float sHT[64][64];   // [k_local][node]
    __shared__ float sW2[64][64];   // [k_local][feat]

    int tid = threadIdx.x;
    int i0 = blockIdx.x * 64;
    if (tid < 128) {
        sW1[tid]       = W1[tid];
        sW1[128 + tid] = W1[128 + tid];
        sW1[256 + tid] = W1[256 + tid];
        sb1[tid]       = b1[tid];
    }
    if (tid < 64) {
        int i = i0 + tid;
        if (i < n) {
            sA0[tid] = aggx[3 * i + 0];
            sA1[tid] = aggx[3 * i + 1];
            sA2[tid] = aggx[3 * i + 2];
        } else {
            sA0[tid] = 0.f; sA1[tid] = 0.f; sA2[tid] = 0.f;
        }
    }
    __syncthreads();

    int tx = tid & 15, ty = tid >> 4;
    int nn0 = ty * 4, f0 = tx * 4;
    float acc[4][4] = {};

    for (int c = 0; c < 2; ++c) {
        #pragma unroll
        for (int j = 0; j < 16; ++j) {
            int idx = tid + 256 * j;
            int kl = idx >> 6, nd = idx & 63;
            int k = c * 64 + kl;
            float h = fmaf(sA0[nd], sW1[k],
                      fmaf(sA1[nd], sW1[128 + k],
                      fmaf(sA2[nd], sW1[256 + k], sb1[k])));
            sHT[kl][nd] = fmaxf(h, 0.f);
        }
        const float4* W2c = (const float4*)(W2 + c * 64 * 64);
        float4* sW2v = (float4*)sW2;
        #pragma unroll
        for (int j = 0; j < 4; ++j) sW2v[tid + 256 * j] = W2c[tid + 256 * j];
        __syncthreads();

        #pragma unroll 8
        for (int kl = 0; kl < 64; ++kl) {
            float4 hv = *(const float4*)&sHT[kl][nn0];
            float4 wv = *(const float4*)&sW2[kl][f0];
            acc[0][0] = fmaf(hv.x, wv.x, acc[0][0]);
            acc[0][1] = fmaf(hv.x, wv.y, acc[0][1]);
            acc[0][2] = fmaf(hv.x, wv.z, acc[0][2]);
            acc[0][3] = fmaf(hv.x, wv.w, acc[0][3]);
            acc[1][0] = fmaf(hv.y, wv.x, acc[1][0]);
            acc[1][1] = fmaf(hv.y, wv.y, acc[1][1]);
            acc[1][2] = fmaf(hv.y, wv.z, acc[1][2]);
            acc[1][3] = fmaf(hv.y, wv.w, acc[1][3]);
            acc[2][0] = fmaf(hv.z, wv.x, acc[2][0]);
            acc[2][1] = fmaf(hv.z, wv.y, acc[2][1]);
            acc[2][2] = fmaf(hv.z, wv.z, acc[2][2]);
            acc[2][3] = fmaf(hv.z, wv.w, acc[2][3]);
            acc[3][0] = fmaf(hv.w, wv.x, acc[3][0]);
            acc[3][1] = fmaf(hv.w, wv.y, acc[3][1]);
            acc[3][2] = fmaf(hv.w, wv.z, acc[3][2]);
            acc[3][3] = fmaf(hv.w, wv.w, acc[3][3]);
        }
        __syncthreads();
    }

    #pragma unroll
    for (int nn = 0; nn < 4; ++nn) {
        int i = i0 + nn0 + nn;
        if (i < n) {
            float di = dis[i];
            ushort4 o;
            o.x = f2bf_rne(acc[nn][0] * di);
            o.y = f2bf_rne(acc[nn][1] * di);
            o.z = f2bf_rne(acc[nn][2] * di);
            o.w = f2bf_rne(acc[nn][3] * di);
            *(ushort4*)&ts[(size_t)i * 64 + f0] = o;
        }
    }
}

// Layer-2 gather + relu + fused mean pool, FEATURE-partitioned across XCDs.
// Group g=bid&7 owns features [8g,8g+8) = one 16B uint4 per ts row
// (per-XCD ts footprint 0.8MB -> L2-resident). One lane per node.
__global__ __launch_bounds__(256) void k_gather2_fp(
        const int* __restrict__ rs, const int* __restrict__ eidx,
        const uint4* __restrict__ ts, const float* __restrict__ dis,
        const float* __restrict__ b2, float* __restrict__ gacc, int n) {
    __shared__ float sred[256 * 8];
    int grp = blockIdx.x & (NXCD - 1);
    int tid = threadIdx.x;
    int i = (blockIdx.x >> 3) * blockDim.x + tid;   // node id

    float acc[8] = {0.f, 0.f, 0.f, 0.f, 0.f, 0.f, 0.f, 0.f};
    float hg[8]  = {0.f, 0.f, 0.f, 0.f, 0.f, 0.f, 0.f, 0.f};

    if (i < n) {
        uint4 v = ts[(size_t)i * 8 + grp];           // self term
        acc[0] = bflo(v.x); acc[1] = bfhi(v.x);
        acc[2] = bflo(v.y); acc[3] = bfhi(v.y);
        acc[4] = bflo(v.z); acc[5] = bfhi(v.z);
        acc[6] = bflo(v.w); acc[7] = bfhi(v.w);
        int p = rs[i], p1 = rs[i + 1];
        for (; p + 3 < p1; p += 4) {                 // 4 rows in flight
            int s0 = eidx[p], s1 = eidx[p + 1], s2 = eidx[p + 2], s3 = eidx[p + 3];
            uint4 a = ts[(size_t)s0 * 8 + grp];
            uint4 b = ts[(size_t)s1 * 8 + grp];
            uint4 c = ts[(size_t)s2 * 8 + grp];
            uint4 d = ts[(size_t)s3 * 8 + grp];
            acc[0] += bflo(a.x) + bflo(b.x) + bflo(c.x) + bflo(d.x);
            acc[1] += bfhi(a.x) + bfhi(b.x) + bfhi(c.x) + bfhi(d.x);
            acc[2] += bflo(a.y) + bflo(b.y) + bflo(c.y) + bflo(d.y);
            acc[3] += bfhi(a.y) + bfhi(b.y) + bfhi(c.y) + bfhi(d.y);
            acc[4] += bflo(a.z) + bflo(b.z) + bflo(c.z) + bflo(d.z);
            acc[5] += bfhi(a.z) + bfhi(b.z) + bfhi(c.z) + bfhi(d.z);
            acc[6] += bflo(a.w) + bflo(b.w) + bflo(c.w) + bflo(d.w);
            acc[7] += bfhi(a.w) + bfhi(b.w) + bfhi(c.w) + bfhi(d.w);
        }
        for (; p < p1; ++p) {
            uint4 a = ts[(size_t)eidx[p] * 8 + grp];
            acc[0] += bflo(a.x); acc[1] += bfhi(a.x);
            acc[2] += bflo(a.y); acc[3] += bfhi(a.y);
            acc[4] += bflo(a.z); acc[5] += bfhi(a.z);
            acc[6] += bflo(a.w); acc[7] += bfhi(a.w);
        }
        float di = dis[i];
        #pragma unroll
        for (int j = 0; j < 8; ++j)
            hg[j] = fmaxf(fmaf(acc[j], di, b2[grp * 8 + j]), 0.f);
    }

    #pragma unroll
    for (int j = 0; j < 8; ++j) sred[tid * 8 + j] = hg[j];
    __syncthreads();
    for (int off = 128; off; off >>= 1) {
        if (tid < off) {
            #pragma unroll
            for (int j = 0; j < 8; ++j)
                sred[tid * 8 + j] += sred[(tid + off) * 8 + j];
        }
        __syncthreads();
    }
    if (tid < 8) atomicAdd(&gacc[grp * 8 + tid], sred[tid]);
}

// out[c] = (1/N) * sum_k g[k] * Wfc[k,c] + bfc[c]; single wave.
__global__ void k_final(const float* __restrict__ g_accum, const float* __restrict__ Wfc,
                        const float* __restrict__ bfc, float* __restrict__ out, float inv_n) {
    int lane = threadIdx.x;   // 0..63
    float gk = g_accum[lane] * inv_n;
    #pragma unroll
    for (int c = 0; c < 3; ++c) {
        float p = gk * Wfc[lane * 3 + c];
        #pragma unroll
        for (int off = 32; off > 0; off >>= 1) p += __shfl_down(p, off);
        if (lane == 0) out[c] = p + bfc[c];
    }
}

extern "C" void kernel_launch(void* const* d_in, const int* in_sizes, int n_in,
                              void* d_out, int out_size, void* d_ws, size_t ws_size,
                              hipStream_t stream) {
    const float* x   = (const float*)d_in[0];
    const int*   ei  = (const int*)d_in[1];
    const float* W1  = (const float*)d_in[2];
    const float* b1  = (const float*)d_in[3];
    const float* W2  = (const float*)d_in[4];
    const float* b2  = (const float*)d_in[5];
    const float* Wfc = (const float*)d_in[6];
    const float* bfc = (const float*)d_in[7];

    const int N = in_sizes[0] / 3;      // 50000
    const int E = in_sizes[1] / 2;      // 600000
    const int* src = ei;
    const int* dst = ei + E;
    const int NB = (N + 255) / 256;     // 196 scan blocks (<= 256)
    const int NPRG = (N + NXCD - 1) / NXCD;   // 6250 nodes per XCD group

    // Workspace layout (4B units):
    //   dis   : N        @ 0
    //   cnt   : N (int)  @ N        (zeroed by k_zero)
    //   gacc  : 64       @ 2N       (zeroed by k_zero)
    //   rs    : N+1(int) @ 2N+64
    //   cur   : N (int)  @ 3N+80
    //   bsum  : 256(int) @ 4N+80
    //   aggx  : 3N       @ 4N+336
    //   xs    : 3N       @ 7N+336
    //   eidx  : E (int)  @ 10N+336
    //   ts    : 64N bf16 (32N floats) @ 10N+336+E   (16B-aligned)
    float* ws = (float*)d_ws;
    float* dis   = ws;
    int*   cnt   = (int*)(ws + (size_t)N);
    float* gacc  = ws + (size_t)2 * N;
    int*   rs    = (int*)(ws + (size_t)2 * N + 64);
    int*   cur   = (int*)(ws + (size_t)3 * N + 80);
    int*   bsum  = (int*)(ws + (size_t)4 * N + 80);
    float* aggx  = ws + (size_t)4 * N + 336;
    float* xs    = ws + (size_t)7 * N + 336;
    int*   eidx  = (int*)(ws + (size_t)10 * N + 336);
    unsigned short* ts = (unsigned short*)(ws + (size_t)10 * N + 336 + (size_t)E);

    int nwords4 = (N + 64) / 4;
    k_zero<<<(nwords4 + 255) / 256, 256, 0, stream>>>((int4*)cnt, nwords4);

    k_count_p<<<2048, 256, 0, stream>>>(dst, cnt, E, NPRG, N);
    k_bsum<<<NB, 256, 0, stream>>>(cnt, bsum, N);
    k_scan2<<<NB, 256, 0, stream>>>(cnt, bsum, NB, rs, cur, dis, x, xs, N, E);
    k_csr_p<<<2048, 256, 0, stream>>>(src, dst, cur, eidx, E, NPRG, N);
    k_aggx<<<(N * 8 + 255) / 256, 256, 0, stream>>>(xs, dis, rs, eidx, aggx, N);
    k_mlp<<<(N + 63) / 64, 256, 0, stream>>>(aggx, W1, b1, W2, dis, ts, N);
    k_gather2_fp<<<NB * NXCD, 256, 0, stream>>>(rs, eidx, (const uint4*)ts, dis, b2, gacc, N);
    k_final<<<1, 64, 0, stream>>>(gacc, Wfc, bfc, (float*)d_out, 1.0f / (float)N);
}

// Round 11
// 133.068 us; speedup vs baseline: 1.2367x; 1.2367x over previous
//
#include <hip/hip_runtime.h>

// GCN 2-layer + mean-pool + FC for MI355X (gfx950).
// Round 11: REVERT round-10's feature-partitioned gather (4x line over-fetch,
// FETCH 84->210MB, 66us). Restore round-9 full-row 16-lane gather. One new
// change: fuse k_aggx into k_mlp (phase 1 computes the block's 64 node
// aggregates, xs is 600KB L2-resident) -> one fewer dispatch + no aggx
// round-trip.
//
// Pipeline:
//   zero cnt+gacc
//   count (XCD dst-partitioned); bsum+scan2 -> rs/cur, dis, xs = x*dis
//   csr (XCD dst-partitioned): eidx[pos] = src
//   mlp (fused): a(i) = dis[i]*(sum xs[s] + xs[i]);
//                ts[i,:] = bf16( dis[i] * ( relu(a@W1+b1) @ W2 ) )
//   gather2: h2 = relu(dis*(sum ts[s]+ts[i])+b2); gacc += colsum
//   out = gacc/N @ Wfc + bfc

#define NXCD 8

__device__ inline unsigned short f2bf_rne(float f) {
    unsigned u = __float_as_uint(f);
    return (unsigned short)((u + 0x7FFFu + ((u >> 16) & 1u)) >> 16);
}
__device__ inline float bf2f(unsigned short b) {
    return __uint_as_float((unsigned)b << 16);
}

// Zero nwords4 int4's (16B each) starting at p (16B-aligned).
__global__ void k_zero(int4* __restrict__ p, int nwords4) {
    int i = blockIdx.x * blockDim.x + threadIdx.x;
    if (i < nwords4) p[i] = make_int4(0, 0, 0, 0);
}

// XCD-partitioned histogram: group (bid&7) counts only dst in its range.
__global__ void k_count_p(const int* __restrict__ dst, int* __restrict__ cnt,
                          int E, int nprg, int n) {
    int grp = blockIdx.x & (NXCD - 1);
    int lo = grp * nprg;
    int hi = min(lo + nprg, n);
    int bIn = blockIdx.x >> 3;
    int nBIn = gridDim.x >> 3;
    for (int e = bIn * blockDim.x + threadIdx.x; e < E; e += nBIn * blockDim.x) {
        int d = dst[e];
        if (d >= lo && d < hi) atomicAdd(&cnt[d], 1);
    }
}

// Phase A: per-block (256-elem chunk) reduction of cnt -> bsum[block].
__global__ void k_bsum(const int* __restrict__ cnt, int* __restrict__ bsum, int n) {
    __shared__ int red[256];
    int tid = threadIdx.x;
    int i = blockIdx.x * 256 + tid;
    red[tid] = (i < n) ? cnt[i] : 0;
    __syncthreads();
    #pragma unroll
    for (int off = 128; off; off >>= 1) {
        if (tid < off) red[tid] += red[tid + off];
        __syncthreads();
    }
    if (tid == 0) bsum[blockIdx.x] = red[0];
}

// Phase B: each block redundantly scans bsum (nb<=256), then scans its own
// 256-elem cnt chunk in LDS; writes rs, cur, dis, xs=x*dis. rs[n]=E.
__global__ void k_scan2(const int* __restrict__ cnt, const int* __restrict__ bsum,
                        int nb, int* __restrict__ rs, int* __restrict__ cur,
                        float* __restrict__ dis, const float* __restrict__ x,
                        float* __restrict__ xs, int n, int Etot) {
    __shared__ int sb[256];
    __shared__ int sc[256];
    int tid = threadIdx.x;
    sb[tid] = (tid < nb) ? bsum[tid] : 0;
    __syncthreads();
    #pragma unroll
    for (int off = 1; off < 256; off <<= 1) {
        int v = (tid >= off) ? sb[tid - off] : 0;
        __syncthreads();
        sb[tid] += v;
        __syncthreads();
    }
    int boff = (blockIdx.x > 0) ? sb[blockIdx.x - 1] : 0;

    int i = blockIdx.x * 256 + tid;
    int c = (i < n) ? cnt[i] : 0;
    sc[tid] = c;
    __syncthreads();
    #pragma unroll
    for (int off = 1; off < 256; off <<= 1) {
        int v = (tid >= off) ? sc[tid - off] : 0;
        __syncthreads();
        sc[tid] += v;
        __syncthreads();
    }
    if (i < n) {
        int r = boff + sc[tid] - c;   // exclusive prefix
        rs[i] = r;
        cur[i] = r;
        float d = rsqrtf((float)c + 1.0f);
        dis[i] = d;
        xs[3 * i + 0] = x[3 * i + 0] * d;
        xs[3 * i + 1] = x[3 * i + 1] * d;
        xs[3 * i + 2] = x[3 * i + 2] * d;
    }
    if (i == 0) rs[n] = Etot;
}

// XCD-partitioned CSR scatter: group (bid&7) owns dst range -> eidx region.
__global__ void k_csr_p(const int* __restrict__ src, const int* __restrict__ dst,
                        int* __restrict__ cur, int* __restrict__ eidx,
                        int E, int nprg, int n) {
    int grp = blockIdx.x & (NXCD - 1);
    int lo = grp * nprg;
    int hi = min(lo + nprg, n);
    int bIn = blockIdx.x >> 3;
    int nBIn = gridDim.x >> 3;
    for (int e = bIn * blockDim.x + threadIdx.x; e < E; e += nBIn * blockDim.x) {
        int d = dst[e];
        if (d >= lo && d < hi) {
            int pos = atomicAdd(&cur[d], 1);
            eidx[pos] = src[e];
        }
    }
}

// Fused layer-1 aggregate + tiled MLP for a 64-node tile per block.
// Phase 1: 4 lanes/node gather  a(i) = dis[i]*(sum_s xs[s] + xs[i]) -> LDS.
// Phase 2: H^T chunk in LDS [k][node]; W2 chunk [k][feat]; 4x4 acc/thread.
// Epilogue: ts[i,:] = bf16(acc * dis[i]).
__global__ __launch_bounds__(256) void k_mlp(const float* __restrict__ xs,
                                             const float* __restrict__ dis,
                                             const int* __restrict__ rs,
                                             const int* __restrict__ eidx,
                                             const float* __restrict__ W1,
                                             const float* __restrict__ b1,
                                             const float* __restrict__ W2,
                                             unsigned short* __restrict__ ts, int n) {
    __shared__ float sA0[64], sA1[64], sA2[64];
    __shared__ float sW1[3 * 128];
    __shared__ float sb1[128];
    __shared__ float sHT[64][64];   // [k_local][node]
    __shared__ float sW2[64][64];   // [k_local][feat]

    int tid = threadIdx.x;
    int i0 = blockIdx.x * 64;
    if (tid < 128) {
        sW1[tid]       = W1[tid];
        sW1[128 + tid] = W1[128 + tid];
        sW1[256 + tid] = W1[256 + tid];
        sb1[tid]       = b1[tid];
    }

    // Phase 1: per-node aggregate, 4 lanes per node (64 nodes x 4 = 256).
    {
        int nd = tid >> 2;          // node slot 0..63
        int sub = tid & 3;
        int i = i0 + nd;
        float a0 = 0.f, a1 = 0.f, a2 = 0.f;
        if (i < n) {
            int p0 = rs[i], p1 = rs[i + 1];
            for (int p = p0 + sub; p < p1; p += 4) {
                int s = eidx[p];
                a0 += xs[3 * s + 0];
                a1 += xs[3 * s + 1];
                a2 += xs[3 * s + 2];
            }
        }
        #pragma unroll
        for (int m = 2; m; m >>= 1) {   // reduce within 4-lane group
            a0 += __shfl_xor(a0, m);
            a1 += __shfl_xor(a1, m);
            a2 += __shfl_xor(a2, m);
        }
        if (sub == 0) {
            if (i < n) {
                float di = dis[i];
                sA0[nd] = di * (a0 + xs[3 * i + 0]);
                sA1[nd] = di * (a1 + xs[3 * i + 1]);
                sA2[nd] = di * (a2 + xs[3 * i + 2]);
            } else {
                sA0[nd] = 0.f; sA1[nd] = 0.f; sA2[nd] = 0.f;
            }
        }
    }
    __syncthreads();

    int tx = tid & 15, ty = tid >> 4;
    int nn0 = ty * 4, f0 = tx * 4;
    float acc[4][4] = {};

    for (int c = 0; c < 2; ++c) {
        #pragma unroll
        for (int j = 0; j < 16; ++j) {
            int idx = tid + 256 * j;
            int kl = idx >> 6, nd = idx & 63;
            int k = c * 64 + kl;
            float h = fmaf(sA0[nd], sW1[k],
                      fmaf(sA1[nd], sW1[128 + k],
                      fmaf(sA2[nd], sW1[256 + k], sb1[k])));
            sHT[kl][nd] = fmaxf(h, 0.f);
        }
        const float4* W2c = (const float4*)(W2 + c * 64 * 64);
        float4* sW2v = (float4*)sW2;
        #pragma unroll
        for (int j = 0; j < 4; ++j) sW2v[tid + 256 * j] = W2c[tid + 256 * j];
        __syncthreads();

        #pragma unroll 8
        for (int kl = 0; kl < 64; ++kl) {
            float4 hv = *(const float4*)&sHT[kl][nn0];
            float4 wv = *(const float4*)&sW2[kl][f0];
            acc[0][0] = fmaf(hv.x, wv.x, acc[0][0]);
            acc[0][1] = fmaf(hv.x, wv.y, acc[0][1]);
            acc[0][2] = fmaf(hv.x, wv.z, acc[0][2]);
            acc[0][3] = fmaf(hv.x, wv.w, acc[0][3]);
            acc[1][0] = fmaf(hv.y, wv.x, acc[1][0]);
            acc[1][1] = fmaf(hv.y, wv.y, acc[1][1]);
            acc[1][2] = fmaf(hv.y, wv.z, acc[1][2]);
            acc[1][3] = fmaf(hv.y, wv.w, acc[1][3]);
            acc[2][0] = fmaf(hv.z, wv.x, acc[2][0]);
            acc[2][1] = fmaf(hv.z, wv.y, acc[2][1]);
            acc[2][2] = fmaf(hv.z, wv.z, acc[2][2]);
            acc[2][3] = fmaf(hv.z, wv.w, acc[2][3]);
            acc[3][0] = fmaf(hv.w, wv.x, acc[3][0]);
            acc[3][1] = fmaf(hv.w, wv.y, acc[3][1]);
            acc[3][2] = fmaf(hv.w, wv.z, acc[3][2]);
            acc[3][3] = fmaf(hv.w, wv.w, acc[3][3]);
        }
        __syncthreads();
    }

    #pragma unroll
    for (int nn = 0; nn < 4; ++nn) {
        int i = i0 + nn0 + nn;
        if (i < n) {
            float di = dis[i];
            ushort4 o;
            o.x = f2bf_rne(acc[nn][0] * di);
            o.y = f2bf_rne(acc[nn][1] * di);
            o.z = f2bf_rne(acc[nn][2] * di);
            o.w = f2bf_rne(acc[nn][3] * di);
            *(ushort4*)&ts[(size_t)i * 64 + f0] = o;
        }
    }
}

// Layer-2 gather + relu + fused mean pool, bf16 rows (128 B). (round-9 version)
// 16 lanes per node (ushort4 over 64 features), 4 nodes/wave, 4-edge unroll.
__global__ void k_gather2(const int* __restrict__ rs, const int* __restrict__ eidx,
                          const ushort4* __restrict__ ts4, const float* __restrict__ dis,
                          const float* __restrict__ b2, float* __restrict__ gacc, int n) {
    __shared__ float sred[256 * 4];
    int tid = threadIdx.x;
    int fl = tid & 15;
    int gid = blockIdx.x * (blockDim.x >> 4) + (tid >> 4);
    int ng = gridDim.x * (blockDim.x >> 4);
    float4 b2v = ((const float4*)b2)[fl];
    float4 accg = make_float4(0.f, 0.f, 0.f, 0.f);

    for (int i = gid; i < n; i += ng) {
        ushort4 sv = ts4[(size_t)i * 16 + fl];   // self term
        float4 acc = make_float4(bf2f(sv.x), bf2f(sv.y), bf2f(sv.z), bf2f(sv.w));
        int p = rs[i], p1 = rs[i + 1];
        for (; p + 3 < p1; p += 4) {
            int s0 = eidx[p], s1 = eidx[p + 1], s2 = eidx[p + 2], s3 = eidx[p + 3];
            ushort4 u0 = ts4[(size_t)s0 * 16 + fl];
            ushort4 u1 = ts4[(size_t)s1 * 16 + fl];
            ushort4 u2 = ts4[(size_t)s2 * 16 + fl];
            ushort4 u3 = ts4[(size_t)s3 * 16 + fl];
            acc.x += bf2f(u0.x) + bf2f(u1.x) + bf2f(u2.x) + bf2f(u3.x);
            acc.y += bf2f(u0.y) + bf2f(u1.y) + bf2f(u2.y) + bf2f(u3.y);
            acc.z += bf2f(u0.z) + bf2f(u1.z) + bf2f(u2.z) + bf2f(u3.z);
            acc.w += bf2f(u0.w) + bf2f(u1.w) + bf2f(u2.w) + bf2f(u3.w);
        }
        for (; p < p1; ++p) {
            int s = eidx[p];
            ushort4 u = ts4[(size_t)s * 16 + fl];
            acc.x += bf2f(u.x); acc.y += bf2f(u.y);
            acc.z += bf2f(u.z); acc.w += bf2f(u.w);
        }
        float di = dis[i];
        accg.x += fmaxf(fmaf(acc.x, di, b2v.x), 0.f);
        accg.y += fmaxf(fmaf(acc.y, di, b2v.y), 0.f);
        accg.z += fmaxf(fmaf(acc.z, di, b2v.z), 0.f);
        accg.w += fmaxf(fmaf(acc.w, di, b2v.w), 0.f);
    }

    sred[tid * 4 + 0] = accg.x;
    sred[tid * 4 + 1] = accg.y;
    sred[tid * 4 + 2] = accg.z;
    sred[tid * 4 + 3] = accg.w;
    __syncthreads();
    if (tid < 64) {
        float v = 0.f;
        #pragma unroll
        for (int g = 0; g < 16; ++g) v += sred[g * 64 + tid];
        atomicAdd(&gacc[tid], v);
    }
}

// out[c] = (1/N) * sum_k g[k] * Wfc[k,c] + bfc[c]; single wave.
__global__ void k_final(const float* __restrict__ g_accum, const float* __restrict__ Wfc,
                        const float* __restrict__ bfc, float* __restrict__ out, float inv_n) {
    int lane = threadIdx.x;   // 0..63
    float gk = g_accum[lane] * inv_n;
    #pragma unroll
    for (int c = 0; c < 3; ++c) {
        float p = gk * Wfc[lane * 3 + c];
        #pragma unroll
        for (int off = 32; off > 0; off >>= 1) p += __shfl_down(p, off);
        if (lane == 0) out[c] = p + bfc[c];
    }
}

extern "C" void kernel_launch(void* const* d_in, const int* in_sizes, int n_in,
                              void* d_out, int out_size, void* d_ws, size_t ws_size,
                              hipStream_t stream) {
    const float* x   = (const float*)d_in[0];
    const int*   ei  = (const int*)d_in[1];
    const float* W1  = (const float*)d_in[2];
    const float* b1  = (const float*)d_in[3];
    const float* W2  = (const float*)d_in[4];
    const float* b2  = (const float*)d_in[5];
    const float* Wfc = (const float*)d_in[6];
    const float* bfc = (const float*)d_in[7];

    const int N = in_sizes[0] / 3;      // 50000
    const int E = in_sizes[1] / 2;      // 600000
    const int* src = ei;
    const int* dst = ei + E;
    const int NB = (N + 255) / 256;     // 196 scan blocks (<= 256)
    const int NPRG = (N + NXCD - 1) / NXCD;   // 6250 nodes per XCD group

    // Workspace layout (4B units):
    //   dis   : N        @ 0
    //   cnt   : N (int)  @ N        (zeroed by k_zero)
    //   gacc  : 64       @ 2N       (zeroed by k_zero)
    //   rs    : N+1(int) @ 2N+64
    //   cur   : N (int)  @ 3N+80
    //   bsum  : 256(int) @ 4N+80
    //   xs    : 3N       @ 4N+336
    //   eidx  : E (int)  @ 7N+336
    //   ts    : 64N bf16 (32N floats) @ 7N+336+E   (16B-aligned)
    float* ws = (float*)d_ws;
    float* dis   = ws;
    int*   cnt   = (int*)(ws + (size_t)N);
    float* gacc  = ws + (size_t)2 * N;
    int*   rs    = (int*)(ws + (size_t)2 * N + 64);
    int*   cur   = (int*)(ws + (size_t)3 * N + 80);
    int*   bsum  = (int*)(ws + (size_t)4 * N + 80);
    float* xs    = ws + (size_t)4 * N + 336;
    int*   eidx  = (int*)(ws + (size_t)7 * N + 336);
    unsigned short* ts = (unsigned short*)(ws + (size_t)7 * N + 336 + (size_t)E);

    int nwords4 = (N + 64) / 4;
    k_zero<<<(nwords4 + 255) / 256, 256, 0, stream>>>((int4*)cnt, nwords4);

    k_count_p<<<2048, 256, 0, stream>>>(dst, cnt, E, NPRG, N);
    k_bsum<<<NB, 256, 0, stream>>>(cnt, bsum, N);
    k_scan2<<<NB, 256, 0, stream>>>(cnt, bsum, NB, rs, cur, dis, x, xs, N, E);
    k_csr_p<<<2048, 256, 0, stream>>>(src, dst, cur, eidx, E, NPRG, N);
    k_mlp<<<(N + 63) / 64, 256, 0, stream>>>(xs, dis, rs, eidx, W1, b1, W2, ts, N);
    k_gather2<<<2048, 256, 0, stream>>>(rs, eidx, (const ushort4*)ts, dis, b2, gacc, N);
    k_final<<<1, 64, 0, stream>>>(gacc, Wfc, bfc, (float*)d_out, 1.0f / (float)N);
}

// Round 12
// 131.026 us; speedup vs baseline: 1.2560x; 1.0156x over previous
//
#include <hip/hip_runtime.h>

// GCN 2-layer + mean-pool + FC for MI355X (gfx950).
// Round 12: (A) ts stored as fp8 e4m3 via HW cvt (row=64B=1 line; whole
// array 3.2MB -> per-XCD-L2-resident; mean-pool averages the quant noise to
// ~1e-4, 15x under threshold). (B) xs padded to float4 -> 1 vector load per
// edge in mlp phase-1 instead of 3 scalar stride-3 loads.
//
// Pipeline:
//   zero cnt+gacc
//   count (XCD dst-partitioned); bsum+scan2 -> rs/cur, dis, xs4 = {x*dis,0}
//   csr (XCD dst-partitioned): eidx[pos] = src
//   mlp (fused): a(i) = dis[i]*(sum xs4[s] + xs4[i]);
//                ts[i,:] = fp8( dis[i] * ( relu(a@W1+b1) @ W2 ) )
//   gather2: h2 = relu(dis*(sum ts[s]+ts[i])+b2); gacc += colsum
//   out = gacc/N @ Wfc + bfc

#define NXCD 8

// Zero nwords4 int4's (16B each) starting at p (16B-aligned).
__global__ void k_zero(int4* __restrict__ p, int nwords4) {
    int i = blockIdx.x * blockDim.x + threadIdx.x;
    if (i < nwords4) p[i] = make_int4(0, 0, 0, 0);
}

// XCD-partitioned histogram: group (bid&7) counts only dst in its range.
__global__ void k_count_p(const int* __restrict__ dst, int* __restrict__ cnt,
                          int E, int nprg, int n) {
    int grp = blockIdx.x & (NXCD - 1);
    int lo = grp * nprg;
    int hi = min(lo + nprg, n);
    int bIn = blockIdx.x >> 3;
    int nBIn = gridDim.x >> 3;
    for (int e = bIn * blockDim.x + threadIdx.x; e < E; e += nBIn * blockDim.x) {
        int d = dst[e];
        if (d >= lo && d < hi) atomicAdd(&cnt[d], 1);
    }
}

// Phase A: per-block (256-elem chunk) reduction of cnt -> bsum[block].
__global__ void k_bsum(const int* __restrict__ cnt, int* __restrict__ bsum, int n) {
    __shared__ int red[256];
    int tid = threadIdx.x;
    int i = blockIdx.x * 256 + tid;
    red[tid] = (i < n) ? cnt[i] : 0;
    __syncthreads();
    #pragma unroll
    for (int off = 128; off; off >>= 1) {
        if (tid < off) red[tid] += red[tid + off];
        __syncthreads();
    }
    if (tid == 0) bsum[blockIdx.x] = red[0];
}

// Phase B: each block redundantly scans bsum (nb<=256), then scans its own
// 256-elem cnt chunk in LDS; writes rs, cur, dis, xs4={x*dis,0}. rs[n]=E.
__global__ void k_scan2(const int* __restrict__ cnt, const int* __restrict__ bsum,
                        int nb, int* __restrict__ rs, int* __restrict__ cur,
                        float* __restrict__ dis, const float* __restrict__ x,
                        float4* __restrict__ xs4, int n, int Etot) {
    __shared__ int sb[256];
    __shared__ int sc[256];
    int tid = threadIdx.x;
    sb[tid] = (tid < nb) ? bsum[tid] : 0;
    __syncthreads();
    #pragma unroll
    for (int off = 1; off < 256; off <<= 1) {
        int v = (tid >= off) ? sb[tid - off] : 0;
        __syncthreads();
        sb[tid] += v;
        __syncthreads();
    }
    int boff = (blockIdx.x > 0) ? sb[blockIdx.x - 1] : 0;

    int i = blockIdx.x * 256 + tid;
    int c = (i < n) ? cnt[i] : 0;
    sc[tid] = c;
    __syncthreads();
    #pragma unroll
    for (int off = 1; off < 256; off <<= 1) {
        int v = (tid >= off) ? sc[tid - off] : 0;
        __syncthreads();
        sc[tid] += v;
        __syncthreads();
    }
    if (i < n) {
        int r = boff + sc[tid] - c;   // exclusive prefix
        rs[i] = r;
        cur[i] = r;
        float d = rsqrtf((float)c + 1.0f);
        dis[i] = d;
        xs4[i] = make_float4(x[3 * i + 0] * d, x[3 * i + 1] * d, x[3 * i + 2] * d, 0.f);
    }
    if (i == 0) rs[n] = Etot;
}

// XCD-partitioned CSR scatter: group (bid&7) owns dst range -> eidx region.
__global__ void k_csr_p(const int* __restrict__ src, const int* __restrict__ dst,
                        int* __restrict__ cur, int* __restrict__ eidx,
                        int E, int nprg, int n) {
    int grp = blockIdx.x & (NXCD - 1);
    int lo = grp * nprg;
    int hi = min(lo + nprg, n);
    int bIn = blockIdx.x >> 3;
    int nBIn = gridDim.x >> 3;
    for (int e = bIn * blockDim.x + threadIdx.x; e < E; e += nBIn * blockDim.x) {
        int d = dst[e];
        if (d >= lo && d < hi) {
            int pos = atomicAdd(&cur[d], 1);
            eidx[pos] = src[e];
        }
    }
}

// Fused layer-1 aggregate + tiled MLP for a 64-node tile per block.
// Phase 1: 4 lanes/node gather  a(i) = dis[i]*(sum_s xs4[s] + xs4[i]) -> LDS.
// Phase 2: H^T chunk in LDS [k][node]; W2 chunk [k][feat]; 4x4 acc/thread.
// Epilogue: ts[i,:] = fp8(acc * dis[i]) packed 4/thread into one dword.
__global__ __launch_bounds__(256) void k_mlp(const float4* __restrict__ xs4,
                                             const float* __restrict__ dis,
                                             const int* __restrict__ rs,
                                             const int* __restrict__ eidx,
                                             const float* __restrict__ W1,
                                             const float* __restrict__ b1,
                                             const float* __restrict__ W2,
                                             unsigned* __restrict__ ts, int n) {
    __shared__ float sA0[64], sA1[64], sA2[64];
    __shared__ float sW1[3 * 128];
    __shared__ float sb1[128];
    __shared__ float sHT[64][64];   // [k_local][node]
    __shared__ float sW2[64][64];   // [k_local][feat]

    int tid = threadIdx.x;
    int i0 = blockIdx.x * 64;
    if (tid < 128) {
        sW1[tid]       = W1[tid];
        sW1[128 + tid] = W1[128 + tid];
        sW1[256 + tid] = W1[256 + tid];
        sb1[tid]       = b1[tid];
    }

    // Phase 1: per-node aggregate, 4 lanes per node (64 nodes x 4 = 256).
    {
        int nd = tid >> 2;          // node slot 0..63
        int sub = tid & 3;
        int i = i0 + nd;
        float a0 = 0.f, a1 = 0.f, a2 = 0.f;
        if (i < n) {
            int p0 = rs[i], p1 = rs[i + 1];
            for (int p = p0 + sub; p < p1; p += 4) {
                float4 vs = xs4[eidx[p]];
                a0 += vs.x; a1 += vs.y; a2 += vs.z;
            }
        }
        #pragma unroll
        for (int m = 2; m; m >>= 1) {   // reduce within 4-lane group
            a0 += __shfl_xor(a0, m);
            a1 += __shfl_xor(a1, m);
            a2 += __shfl_xor(a2, m);
        }
        if (sub == 0) {
            if (i < n) {
                float di = dis[i];
                float4 vi = xs4[i];
                sA0[nd] = di * (a0 + vi.x);
                sA1[nd] = di * (a1 + vi.y);
                sA2[nd] = di * (a2 + vi.z);
            } else {
                sA0[nd] = 0.f; sA1[nd] = 0.f; sA2[nd] = 0.f;
            }
        }
    }
    __syncthreads();

    int tx = tid & 15, ty = tid >> 4;
    int nn0 = ty * 4, f0 = tx * 4;
    float acc[4][4] = {};

    for (int c = 0; c < 2; ++c) {
        #pragma unroll
        for (int j = 0; j < 16; ++j) {
            int idx = tid + 256 * j;
            int kl = idx >> 6, nd = idx & 63;
            int k = c * 64 + kl;
            float h = fmaf(sA0[nd], sW1[k],
                      fmaf(sA1[nd], sW1[128 + k],
                      fmaf(sA2[nd], sW1[256 + k], sb1[k])));
            sHT[kl][nd] = fmaxf(h, 0.f);
        }
        const float4* W2c = (const float4*)(W2 + c * 64 * 64);
        float4* sW2v = (float4*)sW2;
        #pragma unroll
        for (int j = 0; j < 4; ++j) sW2v[tid + 256 * j] = W2c[tid + 256 * j];
        __syncthreads();

        #pragma unroll 8
        for (int kl = 0; kl < 64; ++kl) {
            float4 hv = *(const float4*)&sHT[kl][nn0];
            float4 wv = *(const float4*)&sW2[kl][f0];
            acc[0][0] = fmaf(hv.x, wv.x, acc[0][0]);
            acc[0][1] = fmaf(hv.x, wv.y, acc[0][1]);
            acc[0][2] = fmaf(hv.x, wv.z, acc[0][2]);
            acc[0][3] = fmaf(hv.x, wv.w, acc[0][3]);
            acc[1][0] = fmaf(hv.y, wv.x, acc[1][0]);
            acc[1][1] = fmaf(hv.y, wv.y, acc[1][1]);
            acc[1][2] = fmaf(hv.y, wv.z, acc[1][2]);
            acc[1][3] = fmaf(hv.y, wv.w, acc[1][3]);
            acc[2][0] = fmaf(hv.z, wv.x, acc[2][0]);
            acc[2][1] = fmaf(hv.z, wv.y, acc[2][1]);
            acc[2][2] = fmaf(hv.z, wv.z, acc[2][2]);
            acc[2][3] = fmaf(hv.z, wv.w, acc[2][3]);
            acc[3][0] = fmaf(hv.w, wv.x, acc[3][0]);
            acc[3][1] = fmaf(hv.w, wv.y, acc[3][1]);
            acc[3][2] = fmaf(hv.w, wv.z, acc[3][2]);
            acc[3][3] = fmaf(hv.w, wv.w, acc[3][3]);
        }
        __syncthreads();
    }

    #pragma unroll
    for (int nn = 0; nn < 4; ++nn) {
        int i = i0 + nn0 + nn;
        if (i < n) {
            float di = dis[i];
            unsigned r = __builtin_amdgcn_cvt_pk_fp8_f32(acc[nn][0] * di, acc[nn][1] * di, 0, false);
            r = __builtin_amdgcn_cvt_pk_fp8_f32(acc[nn][2] * di, acc[nn][3] * di, r, true);
            ts[(size_t)i * 16 + tx] = r;
        }
    }
}

// Layer-2 gather + relu + fused mean pool, fp8 rows (64 B = one cache line).
// 16 lanes per node (one dword = 4 fp8 features each), 4 nodes/wave, 4-edge unroll.
__global__ void k_gather2(const int* __restrict__ rs, const int* __restrict__ eidx,
                          const unsigned* __restrict__ ts, const float* __restrict__ dis,
                          const float* __restrict__ b2, float* __restrict__ gacc, int n) {
    __shared__ float sred[256 * 4];
    int tid = threadIdx.x;
    int fl = tid & 15;
    int gid = blockIdx.x * (blockDim.x >> 4) + (tid >> 4);
    int ng = gridDim.x * (blockDim.x >> 4);
    float4 b2v = ((const float4*)b2)[fl];
    float4 accg = make_float4(0.f, 0.f, 0.f, 0.f);

    for (int i = gid; i < n; i += ng) {
        unsigned sv = ts[(size_t)i * 16 + fl];   // self term
        float4 acc = make_float4(__builtin_amdgcn_cvt_f32_fp8(sv, 0),
                                 __builtin_amdgcn_cvt_f32_fp8(sv, 1),
                                 __builtin_amdgcn_cvt_f32_fp8(sv, 2),
                                 __builtin_amdgcn_cvt_f32_fp8(sv, 3));
        int p = rs[i], p1 = rs[i + 1];
        for (; p + 3 < p1; p += 4) {
            int s0 = eidx[p], s1 = eidx[p + 1], s2 = eidx[p + 2], s3 = eidx[p + 3];
            unsigned a = ts[(size_t)s0 * 16 + fl];
            unsigned b = ts[(size_t)s1 * 16 + fl];
            unsigned c = ts[(size_t)s2 * 16 + fl];
            unsigned d = ts[(size_t)s3 * 16 + fl];
            acc.x += __builtin_amdgcn_cvt_f32_fp8(a, 0) + __builtin_amdgcn_cvt_f32_fp8(b, 0)
                   + __builtin_amdgcn_cvt_f32_fp8(c, 0) + __builtin_amdgcn_cvt_f32_fp8(d, 0);
            acc.y += __builtin_amdgcn_cvt_f32_fp8(a, 1) + __builtin_amdgcn_cvt_f32_fp8(b, 1)
                   + __builtin_amdgcn_cvt_f32_fp8(c, 1) + __builtin_amdgcn_cvt_f32_fp8(d, 1);
            acc.z += __builtin_amdgcn_cvt_f32_fp8(a, 2) + __builtin_amdgcn_cvt_f32_fp8(b, 2)
                   + __builtin_amdgcn_cvt_f32_fp8(c, 2) + __builtin_amdgcn_cvt_f32_fp8(d, 2);
            acc.w += __builtin_amdgcn_cvt_f32_fp8(a, 3) + __builtin_amdgcn_cvt_f32_fp8(b, 3)
                   + __builtin_amdgcn_cvt_f32_fp8(c, 3) + __builtin_amdgcn_cvt_f32_fp8(d, 3);
        }
        for (; p < p1; ++p) {
            unsigned a = ts[(size_t)eidx[p] * 16 + fl];
            acc.x += __builtin_amdgcn_cvt_f32_fp8(a, 0);
            acc.y += __builtin_amdgcn_cvt_f32_fp8(a, 1);
            acc.z += __builtin_amdgcn_cvt_f32_fp8(a, 2);
            acc.w += __builtin_amdgcn_cvt_f32_fp8(a, 3);
        }
        float di = dis[i];
        accg.x += fmaxf(fmaf(acc.x, di, b2v.x), 0.f);
        accg.y += fmaxf(fmaf(acc.y, di, b2v.y), 0.f);
        accg.z += fmaxf(fmaf(acc.z, di, b2v.z), 0.f);
        accg.w += fmaxf(fmaf(acc.w, di, b2v.w), 0.f);
    }

    sred[tid * 4 + 0] = accg.x;
    sred[tid * 4 + 1] = accg.y;
    sred[tid * 4 + 2] = accg.z;
    sred[tid * 4 + 3] = accg.w;
    __syncthreads();
    if (tid < 64) {
        float v = 0.f;
        #pragma unroll
        for (int g = 0; g < 16; ++g) v += sred[g * 64 + tid];
        atomicAdd(&gacc[tid], v);
    }
}

// out[c] = (1/N) * sum_k g[k] * Wfc[k,c] + bfc[c]; single wave.
__global__ void k_final(const float* __restrict__ g_accum, const float* __restrict__ Wfc,
                        const float* __restrict__ bfc, float* __restrict__ out, float inv_n) {
    int lane = threadIdx.x;   // 0..63
    float gk = g_accum[lane] * inv_n;
    #pragma unroll
    for (int c = 0; c < 3; ++c) {
        float p = gk * Wfc[lane * 3 + c];
        #pragma unroll
        for (int off = 32; off > 0; off >>= 1) p += __shfl_down(p, off);
        if (lane == 0) out[c] = p + bfc[c];
    }
}

extern "C" void kernel_launch(void* const* d_in, const int* in_sizes, int n_in,
                              void* d_out, int out_size, void* d_ws, size_t ws_size,
                              hipStream_t stream) {
    const float* x   = (const float*)d_in[0];
    const int*   ei  = (const int*)d_in[1];
    const float* W1  = (const float*)d_in[2];
    const float* b1  = (const float*)d_in[3];
    const float* W2  = (const float*)d_in[4];
    const float* b2  = (const float*)d_in[5];
    const float* Wfc = (const float*)d_in[6];
    const float* bfc = (const float*)d_in[7];

    const int N = in_sizes[0] / 3;      // 50000
    const int E = in_sizes[1] / 2;      // 600000
    const int* src = ei;
    const int* dst = ei + E;
    const int NB = (N + 255) / 256;     // 196 scan blocks (<= 256)
    const int NPRG = (N + NXCD - 1) / NXCD;   // 6250 nodes per XCD group

    // Workspace layout (4B units):
    //   dis   : N        @ 0
    //   cnt   : N (int)  @ N        (zeroed by k_zero)
    //   gacc  : 64       @ 2N       (zeroed by k_zero)
    //   rs    : N+1(int) @ 2N+64
    //   cur   : N (int)  @ 3N+80
    //   bsum  : 256(int) @ 4N+80
    //   xs4   : 4N       @ 4N+336   (16B-aligned: N%4==0, 336%4==0)
    //   eidx  : E (int)  @ 8N+336
    //   ts    : 64N fp8 = 16N dwords @ 8N+336+E  (16B-aligned)
    float* ws = (float*)d_ws;
    float* dis   = ws;
    int*   cnt   = (int*)(ws + (size_t)N);
    float* gacc  = ws + (size_t)2 * N;
    int*   rs    = (int*)(ws + (size_t)2 * N + 64);
    int*   cur   = (int*)(ws + (size_t)3 * N + 80);
    int*   bsum  = (int*)(ws + (size_t)4 * N + 80);
    float4* xs4  = (float4*)(ws + (size_t)4 * N + 336);
    int*   eidx  = (int*)(ws + (size_t)8 * N + 336);
    unsigned* ts = (unsigned*)(ws + (size_t)8 * N + 336 + (size_t)E);

    int nwords4 = (N + 64) / 4;
    k_zero<<<(nwords4 + 255) / 256, 256, 0, stream>>>((int4*)cnt, nwords4);

    k_count_p<<<2048, 256, 0, stream>>>(dst, cnt, E, NPRG, N);
    k_bsum<<<NB, 256, 0, stream>>>(cnt, bsum, N);
    k_scan2<<<NB, 256, 0, stream>>>(cnt, bsum, NB, rs, cur, dis, x, xs4, N, E);
    k_csr_p<<<2048, 256, 0, stream>>>(src, dst, cur, eidx, E, NPRG, N);
    k_mlp<<<(N + 63) / 64, 256, 0, stream>>>(xs4, dis, rs, eidx, W1, b1, W2, ts, N);
    k_gather2<<<2048, 256, 0, stream>>>(rs, eidx, ts, dis, b2, gacc, N);
    k_final<<<1, 64, 0, stream>>>(gacc, Wfc, bfc, (float*)d_out, 1.0f / (float)N);
}